// Round 1
// baseline (163.387 us; speedup 1.0000x reference)
//
#include <hip/hip_runtime.h>
#include <stdint.h>

// Simple exponential smoothing: level_t = (1-a)*level_{t-1} + a*y_t,
// level_0 = y_0 pinned by choosing global initial carry s_{-1} = y_0
// (then level_0 = (1-a)*y0 + a*y0 = y0, recurrence uniform everywhere).
// Output: out[t] = level_t for t in [0, n-2]  (length n-1).
//
// Reduce-then-scan, affine pairs (a,b): s_out = a*s_in + b.
// combine(earlier=(a1,b1), later=(a2,b2)) = (a1*a2, a2*b1 + b2).

#define BLOCK 256
#define SEG   64                 // elements per thread
#define VPT   (SEG / 4)          // float4 per thread
#define CHUNK (BLOCK * SEG)      // 16384 elements per block

// Inclusive Hillis-Steele scan over BLOCK affine pairs in LDS.
__device__ __forceinline__ void block_scan_affine(float* sa, float* sb, int t) {
#pragma unroll
    for (int off = 1; off < BLOCK; off <<= 1) {
        float pa = 1.0f, pb = 0.0f;
        if (t >= off) { pa = sa[t - off]; pb = sb[t - off]; }
        __syncthreads();
        if (t >= off) {
            float ca = sa[t], cb = sb[t];
            sa[t] = pa * ca;
            sb[t] = fmaf(ca, pb, cb);
        }
        __syncthreads();
    }
}

// Pass 1: per-block affine aggregate.
__global__ __launch_bounds__(BLOCK) void k_block_agg(
    const float* __restrict__ y, const float* __restrict__ alpha_p,
    float* __restrict__ aggA, float* __restrict__ aggB, long n)
{
    const int t = threadIdx.x;
    const long base = (long)blockIdx.x * CHUNK + (long)t * SEG;
    const float alpha = alpha_p[0];
    const float oma = 1.0f - alpha;

    float a = 1.0f, s = 0.0f;
    if (base + SEG <= n) {
        const float4* p = (const float4*)(y + base);
#pragma unroll
        for (int v = 0; v < VPT; ++v) {
            float4 q = p[v];
            s = fmaf(oma, s, alpha * q.x);
            s = fmaf(oma, s, alpha * q.y);
            s = fmaf(oma, s, alpha * q.z);
            s = fmaf(oma, s, alpha * q.w);
            a *= oma; a *= oma; a *= oma; a *= oma;
        }
    } else {
        for (int k = 0; k < SEG; ++k) {
            long idx = base + k;
            if (idx < n) { s = fmaf(oma, s, alpha * y[idx]); a *= oma; }
        }
    }

    __shared__ float sa[BLOCK], sb[BLOCK];
    sa[t] = a; sb[t] = s;
    __syncthreads();
    block_scan_affine(sa, sb, t);
    if (t == BLOCK - 1) {
        aggA[blockIdx.x] = sa[t];
        aggB[blockIdx.x] = sb[t];
    }
}

// Pass 2: scan the G block aggregates -> scalar carry (level before block g).
__global__ __launch_bounds__(BLOCK) void k_carry_scan(
    const float* __restrict__ aggA, const float* __restrict__ aggB,
    const float* __restrict__ y, float* __restrict__ carry, int G)
{
    const int t = threadIdx.x;
    const int items = (G + BLOCK - 1) / BLOCK;
    const float y0 = y[0];

    float ta = 1.0f, tb = 0.0f;
    for (int j = 0; j < items; ++j) {
        int g = t * items + j;
        if (g < G) {
            float ca = aggA[g], cb = aggB[g];
            float na = ta * ca;
            float nb = fmaf(ca, tb, cb);
            ta = na; tb = nb;
        }
    }

    __shared__ float sa[BLOCK], sb[BLOCK];
    sa[t] = ta; sb[t] = tb;
    __syncthreads();
    block_scan_affine(sa, sb, t);

    float ea = 1.0f, eb = 0.0f;
    if (t > 0) { ea = sa[t - 1]; eb = sb[t - 1]; }
    for (int j = 0; j < items; ++j) {
        int g = t * items + j;
        if (g < G) {
            carry[g] = fmaf(ea, y0, eb);
            float ca = aggA[g], cb = aggB[g];
            float na = ea * ca;
            float nb = fmaf(ca, eb, cb);
            ea = na; eb = nb;
        }
    }
}

// Pass 3: recompute thread aggregates from register-cached data, block scan
// for per-thread start level, replay and emit.
__global__ __launch_bounds__(BLOCK) void k_emit(
    const float* __restrict__ y, const float* __restrict__ alpha_p,
    const float* __restrict__ carry, float* __restrict__ out, long n)
{
    const int t = threadIdx.x;
    const long base = (long)blockIdx.x * CHUNK + (long)t * SEG;
    const float alpha = alpha_p[0];
    const float oma = 1.0f - alpha;

    const bool full = (base + SEG <= n);
    float4 arr[VPT];
    float a = 1.0f, s = 0.0f;

    if (full) {
        const float4* p = (const float4*)(y + base);
#pragma unroll
        for (int v = 0; v < VPT; ++v) arr[v] = p[v];
#pragma unroll
        for (int v = 0; v < VPT; ++v) {
            s = fmaf(oma, s, alpha * arr[v].x);
            s = fmaf(oma, s, alpha * arr[v].y);
            s = fmaf(oma, s, alpha * arr[v].z);
            s = fmaf(oma, s, alpha * arr[v].w);
            a *= oma; a *= oma; a *= oma; a *= oma;
        }
    } else {
        for (int k = 0; k < SEG; ++k) {
            long idx = base + k;
            if (idx < n) { s = fmaf(oma, s, alpha * y[idx]); a *= oma; }
        }
    }

    __shared__ float sa[BLOCK], sb[BLOCK];
    sa[t] = a; sb[t] = s;
    __syncthreads();
    block_scan_affine(sa, sb, t);

    const float c = carry[blockIdx.x];
    float ea = 1.0f, eb = 0.0f;
    if (t > 0) { ea = sa[t - 1]; eb = sb[t - 1]; }
    float lvl = fmaf(ea, c, eb);   // level just before this thread's segment

    if (full && (base + SEG <= n - 1)) {
        // all SEG outputs in range: vector stores
        float4* o = (float4*)(out + base);
#pragma unroll
        for (int v = 0; v < VPT; ++v) {
            float4 r;
            lvl = fmaf(oma, lvl, alpha * arr[v].x); r.x = lvl;
            lvl = fmaf(oma, lvl, alpha * arr[v].y); r.y = lvl;
            lvl = fmaf(oma, lvl, alpha * arr[v].z); r.z = lvl;
            lvl = fmaf(oma, lvl, alpha * arr[v].w); r.w = lvl;
            o[v] = r;
        }
    } else {
        for (int k = 0; k < SEG; ++k) {
            long idx = base + k;
            if (idx < n) {
                lvl = fmaf(oma, lvl, alpha * y[idx]);
                if (idx < n - 1) out[idx] = lvl;
            }
        }
    }
}

extern "C" void kernel_launch(void* const* d_in, const int* in_sizes, int n_in,
                              void* d_out, int out_size, void* d_ws, size_t ws_size,
                              hipStream_t stream) {
    const float* y     = (const float*)d_in[0];
    const float* alpha = (const float*)d_in[1];
    float* out = (float*)d_out;
    const long n = (long)in_sizes[0];
    const int G = (int)((n + CHUNK - 1) / CHUNK);   // 1024 for n = 2^24

    float* aggA  = (float*)d_ws;       // G floats
    float* aggB  = aggA + G;           // G floats
    float* carry = aggB + G;           // G floats  (12 KiB total)

    k_block_agg<<<G, BLOCK, 0, stream>>>(y, alpha, aggA, aggB, n);
    k_carry_scan<<<1, BLOCK, 0, stream>>>(aggA, aggB, y, carry, G);
    k_emit<<<G, BLOCK, 0, stream>>>(y, alpha, carry, out, n);
}